// Round 5
// baseline (175.972 us; speedup 1.0000x reference)
//
#include <hip/hip_runtime.h>
#include <math.h>

#define ETA 1e-5f
#define MIN_SIGMA 1e-6f

constexpr int NN = 1024;  // N0 == N1
constexpr int ND = 128;   // D

// ws layout (in floats) -- zeroed region first [MAXKEY..DEN]
constexpr size_t OFF_MAXKEY = 0;                       // u32[32]
constexpr size_t OFF_DEN    = 32;                      // f32[32]
constexpr size_t OFF_RW     = 64;                      // f32[32*1024]
constexpr size_t OFF_CW     = OFF_RW + 32 * 1024;      // f32[32*1024]
constexpr size_t OFF_X0N    = OFF_CW + 32 * 1024;      // f32[1024]
constexpr size_t OFF_X1N    = OFF_X0N + 1024;          // f32[1024]
constexpr size_t OFF_AP     = OFF_X1N + 1024;          // f32[32*1024]
constexpr size_t OFF_BP     = OFF_AP + 32 * 1024;      // f32[32*1024]
constexpr size_t OFF_C2     = OFF_BP + 32 * 1024;      // f32[32]
constexpr size_t OFF_DOT    = ((OFF_C2 + 32 + 63) / 64) * 64;  // f32[1024*1024]
// partial-sum arrays (only used if ws_size permits)
constexpr size_t OFF_RWP    = OFF_DOT + 1024 * 1024;   // f32[32][32][1024]
constexpr size_t OFF_CWP    = OFF_RWP + 32 * 32 * 1024;// f32[32][32][1024]
constexpr size_t WS_NEED_FLOATS = OFF_CWP + 32 * 32 * 1024;

__device__ __forceinline__ unsigned fkey(float x) {
  unsigned u = __float_as_uint(x);
  return (u & 0x80000000u) ? ~u : (u | 0x80000000u);
}
__device__ __forceinline__ float funkey(unsigned u) {
  return (u & 0x80000000u) ? __uint_as_float(u & 0x7fffffffu)
                           : __uint_as_float(~u);
}

// ---------------- Ap[b,i], Bp[b,j], c2[b], x0n, x1n ----------------
__global__ __launch_bounds__(256) void k_ab(const float* __restrict__ xt,
                                            const float* __restrict__ tarr,
                                            const float* __restrict__ x0,
                                            const float* __restrict__ x1,
                                            float* __restrict__ ws) {
  __shared__ __align__(16) float xts[ND];
  int b = blockIdx.x >> 2, q = blockIdx.x & 3;
  int tid = threadIdx.x;
  if (tid < ND) xts[tid] = xt[(size_t)b * ND + tid];
  __syncthreads();

  float tb = tarr[b];
  float omt = 1.f - tb;
  float ib2 = 1.f / ((tb + ETA) * (1.f - tb + ETA));

  float xtn = 0.f;
#pragma unroll
  for (int k4 = 0; k4 < ND / 4; k4++) {
    float4 xv = *(const float4*)&xts[k4 * 4];
    xtn += xv.x * xv.x + xv.y * xv.y + xv.z * xv.z + xv.w * xv.w;
  }

  int i = q * 256 + tid;
  float acc0 = 0.f, acc1 = 0.f, n0 = 0.f, n1 = 0.f;
#pragma unroll 8
  for (int k4 = 0; k4 < ND / 4; k4++) {
    float4 xv = *(const float4*)&xts[k4 * 4];
    float4 a = *(const float4*)(x0 + (size_t)i * ND + k4 * 4);
    float4 c = *(const float4*)(x1 + (size_t)i * ND + k4 * 4);
    acc0 += xv.x * a.x + xv.y * a.y + xv.z * a.z + xv.w * a.w;
    acc1 += xv.x * c.x + xv.y * c.y + xv.z * c.z + xv.w * c.w;
    n0 += a.x * a.x + a.y * a.y + a.z * a.z + a.w * a.w;
    n1 += c.x * c.x + c.y * c.y + c.z * c.z + c.w * c.w;
  }
  ws[OFF_AP + (size_t)b * NN + i] =
      fmaf(omt * omt, n0, fmaf(-2.f * omt, acc0, xtn)) * ib2;
  ws[OFF_BP + (size_t)b * NN + i] =
      fmaf(tb * tb, n1, -2.f * tb * acc1) * ib2;
  if (b == 0) {
    ws[OFF_X0N + i] = n0;
    ws[OFF_X1N + i] = n1;
  }
  if (q == 0 && tid == 0) ws[OFF_C2 + b] = 2.f * tb * omt * ib2;
}

// ---------------- k1: GEMM + QPR + per-b max (b-lane) ----
__global__ __launch_bounds__(256) void k1(const float* __restrict__ x0,
                                          const float* __restrict__ x1,
                                          const float* __restrict__ sigw,
                                          float* __restrict__ ws) {
  __shared__ __align__(16) float As[32][36];
  __shared__ __align__(16) float Bs[32][36];
  __shared__ __align__(16) float4 QPRS[32][32];
  __shared__ float ApT[32][33], BpT[32][33];
  __shared__ float x0nS[32], x1nS[32];
  __shared__ unsigned mS[32];

  int tid = threadIdx.x;
  int tx = tid & 15, ty = tid >> 4;
  int i0 = blockIdx.y * 32, j0 = blockIdx.x * 32;

  {
    const float* Ap = ws + OFF_AP;
    const float* Bp = ws + OFF_BP;
#pragma unroll
    for (int rep = 0; rep < 4; rep++) {
      int idx = rep * 256 + tid;
      int bb = idx >> 5, ii = idx & 31;
      ApT[ii][bb] = Ap[(size_t)bb * NN + i0 + ii];
      BpT[ii][bb] = Bp[(size_t)bb * NN + j0 + ii];
    }
    if (tid < 32) {
      x0nS[tid] = ws[OFF_X0N + i0 + tid];
      x1nS[tid] = ws[OFF_X1N + j0 + tid];
      mS[tid] = 0u;
    }
  }

  // GEMM 32x32x128 (2x2 per thread)
  float c00 = 0.f, c01 = 0.f, c10 = 0.f, c11 = 0.f;
  int srow = tid >> 3, sk4 = tid & 7;
  for (int kc = 0; kc < 4; kc++) {
    __syncthreads();
    float4 a = *(const float4*)(x0 + (size_t)(i0 + srow) * ND + kc * 32 + sk4 * 4);
    float4 bb = *(const float4*)(x1 + (size_t)(j0 + srow) * ND + kc * 32 + sk4 * 4);
    As[sk4 * 4 + 0][srow] = a.x;
    As[sk4 * 4 + 1][srow] = a.y;
    As[sk4 * 4 + 2][srow] = a.z;
    As[sk4 * 4 + 3][srow] = a.w;
    Bs[sk4 * 4 + 0][srow] = bb.x;
    Bs[sk4 * 4 + 1][srow] = bb.y;
    Bs[sk4 * 4 + 2][srow] = bb.z;
    Bs[sk4 * 4 + 3][srow] = bb.w;
    __syncthreads();
#pragma unroll
    for (int k = 0; k < 32; k++) {
      float2 av = *(const float2*)&As[k][ty * 2];
      float2 bv = *(const float2*)&Bs[k][tx * 2];
      c00 = fmaf(av.x, bv.x, c00);
      c01 = fmaf(av.x, bv.y, c01);
      c10 = fmaf(av.y, bv.x, c10);
      c11 = fmaf(av.y, bv.y, c11);
    }
  }

  // store dot for k2
  float* dot = ws + OFF_DOT;
  *(float2*)&dot[(size_t)(i0 + ty * 2 + 0) * NN + j0 + tx * 2] = make_float2(c00, c01);
  *(float2*)&dot[(size_t)(i0 + ty * 2 + 1) * NN + j0 + tx * 2] = make_float2(c10, c11);

  // QPR per point (log2 domain)
  float swv = sigw[0];
  float sp = (swv > 20.f) ? swv : log1pf(__expf(swv));
  float dotv[2][2] = {{c00, c01}, {c10, c11}};
#pragma unroll
  for (int r = 0; r < 2; r++) {
#pragma unroll
    for (int c = 0; c < 2; c++) {
      float d01 = x0nS[ty * 2 + r] + x1nS[tx * 2 + c] - 2.f * dotv[r][c];
      float ss = fmaf(sp, sqrtf(fmaxf(d01, 0.f) * (1.f / 128.f)), MIN_SIGMA);
      float Q = -0.72134752044f / (ss * ss);
      float R = -128.f * __log2f(ss);
      QPRS[ty * 2 + r][tx * 2 + c] = make_float4(Q, dotv[r][c] * Q, R, 0.f);
    }
  }
  __syncthreads();

  // pass A: b-lane max
  int b = tid & 31, rep = tid >> 5;
  float c2b = ws[OFF_C2 + b];
  float bpreg[32];
#pragma unroll
  for (int j = 0; j < 32; j++) bpreg[j] = BpT[j][b];
  float m = -3.4e38f;
#pragma unroll
  for (int r = 0; r < 4; r++) {
    int i = rep * 4 + r;
    float ap = ApT[i][b];
#pragma unroll
    for (int j = 0; j < 32; j++) {
      float4 q4 = QPRS[i][j];
      float core = fmaf(ap + bpreg[j], q4.x, fmaf(c2b, q4.y, q4.z));
      m = fmaxf(m, core);
    }
  }
  atomicMax(&mS[b], fkey(m));
  __syncthreads();
  if (tid < 32) atomicMax((unsigned*)ws + OFF_MAXKEY + tid, mS[tid]);
}

// ---------------- k2: exp + row/col/den (b-lane) ---------
// PARTIAL=1: plain stores to rwp/cwp (reduced by kR). PARTIAL=0: atomic flush.
template <int PARTIAL>
__global__ __launch_bounds__(256) void k2(const float* __restrict__ sigw,
                                          float* __restrict__ ws) {
  __shared__ __align__(16) float4 QPRS[32][32];
  __shared__ float ApT[32][33], BpT[32][33];
  __shared__ float colS[32][33], rowS[32][33];
  __shared__ float x0nS[32], x1nS[32];
  __shared__ float denS[32];

  int tid = threadIdx.x;
  int tx = tid & 15, ty = tid >> 4;
  int i0 = blockIdx.y * 32, j0 = blockIdx.x * 32;

  {
    const float* Ap = ws + OFF_AP;
    const float* Bp = ws + OFF_BP;
#pragma unroll
    for (int rep = 0; rep < 4; rep++) {
      int idx = rep * 256 + tid;
      int bb = idx >> 5, ii = idx & 31;
      ApT[ii][bb] = Ap[(size_t)bb * NN + i0 + ii];
      BpT[ii][bb] = Bp[(size_t)bb * NN + j0 + ii];
      colS[ii][bb] = 0.f;
    }
    if (tid < 32) {
      x0nS[tid] = ws[OFF_X0N + i0 + tid];
      x1nS[tid] = ws[OFF_X1N + j0 + tid];
      denS[tid] = 0.f;
    }
  }

  // load dot tile (global, no LDS dependency yet)
  const float* dot = ws + OFF_DOT;
  float2 dv0 = *(const float2*)&dot[(size_t)(i0 + ty * 2 + 0) * NN + j0 + tx * 2];
  float2 dv1 = *(const float2*)&dot[(size_t)(i0 + ty * 2 + 1) * NN + j0 + tx * 2];
  float dotv[2][2] = {{dv0.x, dv0.y}, {dv1.x, dv1.y}};
  float swv = sigw[0];
  float sp = (swv > 20.f) ? swv : log1pf(__expf(swv));

  __syncthreads();  // x0nS/x1nS ready

#pragma unroll
  for (int r = 0; r < 2; r++) {
#pragma unroll
    for (int c = 0; c < 2; c++) {
      float d01 = x0nS[ty * 2 + r] + x1nS[tx * 2 + c] - 2.f * dotv[r][c];
      float ss = fmaf(sp, sqrtf(fmaxf(d01, 0.f) * (1.f / 128.f)), MIN_SIGMA);
      float Q = -0.72134752044f / (ss * ss);
      float R = -128.f * __log2f(ss);
      QPRS[ty * 2 + r][tx * 2 + c] = make_float4(Q, dotv[r][c] * Q, R, 0.f);
    }
  }
  __syncthreads();  // QPRS ready

  // pass B: b-lane accumulation
  int b = tid & 31, rep = tid >> 5;
  float c2b = ws[OFF_C2 + b];
  float m2 = funkey(((const unsigned*)ws)[OFF_MAXKEY + b]);
  float bpreg[32];
#pragma unroll
  for (int j = 0; j < 32; j++) bpreg[j] = BpT[j][b];
  float colreg[32];
#pragma unroll
  for (int j = 0; j < 32; j++) colreg[j] = 0.f;
  float dreg = 0.f;
#pragma unroll
  for (int r = 0; r < 4; r++) {
    int i = rep * 4 + r;
    float ap = ApT[i][b];
    float rs = 0.f;
#pragma unroll
    for (int j = 0; j < 32; j++) {
      float4 q4 = QPRS[i][j];
      float core = fmaf(ap + bpreg[j], q4.x, fmaf(c2b, q4.y, q4.z));
      float w = exp2f(core - m2);
      rs += w;
      colreg[j] += w;
    }
    rowS[i][b] = rs;  // unique owner -> plain store
    dreg += rs;
  }
#pragma unroll
  for (int j = 0; j < 32; j++) atomicAdd(&colS[j][b], colreg[j]);
  atomicAdd(&denS[b], dreg);
  __syncthreads();

  // coalesced flush
  if (PARTIAL) {
    float* rwp = ws + OFF_RWP + (size_t)blockIdx.x * (32 * 1024);  // [jb][b][i]
    float* cwp = ws + OFF_CWP + (size_t)blockIdx.y * (32 * 1024);  // [ib][b][j]
#pragma unroll
    for (int k = 0; k < 4; k++) {
      int idx = k * 256 + tid;
      int bb = idx >> 5, ii = idx & 31;
      rwp[(size_t)bb * NN + i0 + ii] = rowS[ii][bb];
      cwp[(size_t)bb * NN + j0 + ii] = colS[ii][bb];
    }
  } else {
    float* rw = ws + OFF_RW;
    float* cw = ws + OFF_CW;
#pragma unroll
    for (int k = 0; k < 4; k++) {
      int idx = k * 256 + tid;
      int bb = idx >> 5, ii = idx & 31;
      atomicAdd(&rw[(size_t)bb * NN + i0 + ii], rowS[ii][bb]);
      atomicAdd(&cw[(size_t)bb * NN + j0 + ii], colS[ii][bb]);
    }
  }
  if (tid < 32) atomicAdd(ws + OFF_DEN + tid, denS[tid]);
}

// ---------------- kR: reduce partials into rw/cw ----------------
__global__ __launch_bounds__(256) void kR(float* __restrict__ ws) {
  int f = blockIdx.x * 256 + threadIdx.x;  // 0..32767 (= b*1024 + i)
  const float* rwp = ws + OFF_RWP + f;
  const float* cwp = ws + OFF_CWP + f;
  float s0 = 0.f, s1 = 0.f;
#pragma unroll
  for (int p = 0; p < 32; p++) {
    s0 += rwp[(size_t)p * (32 * 1024)];
    s1 += cwp[(size_t)p * (32 * 1024)];
  }
  ws[OFF_RW + f] = s0;
  ws[OFF_CW + f] = s1;
}

// ---------------- k3: weighted combine + output ----------------
__global__ __launch_bounds__(256) void k3(const float* __restrict__ xt,
                                          const float* __restrict__ tarr,
                                          const float* __restrict__ x0,
                                          const float* __restrict__ x1,
                                          const float* __restrict__ ws,
                                          float* __restrict__ out) {
  int b = blockIdx.x >> 2, dq = blockIdx.x & 3;
  int tid = threadIdx.x;
  int d = dq * 32 + (tid & 31);
  int h = tid >> 5;  // 0..7, each handles 128 rows
  const float* rw = ws + OFF_RW + (size_t)b * NN;
  const float* cw = ws + OFF_CW + (size_t)b * NN;
  float a0 = 0.f, a1 = 0.f;
  int ibeg = h * 128;
#pragma unroll 4
  for (int k = 0; k < 128; k++) {
    int i = ibeg + k;
    a0 = fmaf(rw[i], x0[(size_t)i * ND + d], a0);
    a1 = fmaf(cw[i], x1[(size_t)i * ND + d], a1);
  }
  __shared__ float s0[8][32], s1[8][32];
  s0[h][tid & 31] = a0;
  s1[h][tid & 31] = a1;
  __syncthreads();
  if (tid < 32) {
    float A0 = 0.f, A1 = 0.f;
#pragma unroll
    for (int hh = 0; hh < 8; hh++) {
      A0 += s0[hh][tid];
      A1 += s1[hh][tid];
    }
    float tb = tarr[b];
    float den = ws[OFF_DEN + b];
    float ct = (1.f - 2.f * tb) / (2.f * (tb + ETA) * (1.f - tb + ETA));
    float av = -1.f - ct * (1.f - tb);
    float bv = 1.f - ct * tb;
    float den_c = fmaxf(den, 1e-12f);
    out[(size_t)b * ND + d] =
        (ct * xt[(size_t)b * ND + d] * den + av * A0 + bv * A1) / den_c;
  }
}

extern "C" void kernel_launch(void* const* d_in, const int* in_sizes, int n_in,
                              void* d_out, int out_size, void* d_ws, size_t ws_size,
                              hipStream_t stream) {
  const float* xt = (const float*)d_in[0];
  const float* t = (const float*)d_in[1];
  const float* x0 = (const float*)d_in[2];
  const float* x1 = (const float*)d_in[3];
  const float* sw = (const float*)d_in[4];
  float* out = (float*)d_out;
  float* ws = (float*)d_ws;

  bool partial = ws_size >= WS_NEED_FLOATS * sizeof(float);

  if (partial) {
    // only maxkey + den need zeroing; rw/cw are written by kR
    hipMemsetAsync(ws, 0, 64 * sizeof(float), stream);
  } else {
    hipMemsetAsync(ws, 0, OFF_X0N * sizeof(float), stream);
  }

  k_ab<<<128, 256, 0, stream>>>(xt, t, x0, x1, ws);
  k1<<<dim3(32, 32), 256, 0, stream>>>(x0, x1, sw, ws);
  if (partial) {
    k2<1><<<dim3(32, 32), 256, 0, stream>>>(sw, ws);
    kR<<<128, 256, 0, stream>>>(ws);
  } else {
    k2<0><<<dim3(32, 32), 256, 0, stream>>>(sw, ws);
  }
  k3<<<128, 256, 0, stream>>>(xt, t, x0, x1, ws, out);
}

// Round 7
// 164.335 us; speedup vs baseline: 1.0708x; 1.0708x over previous
//
#include <hip/hip_runtime.h>
#include <math.h>

#define ETA 1e-5f
#define MIN_SIGMA 1e-6f

constexpr int NN = 1024;  // N0 == N1
constexpr int ND = 128;   // D

// ws layout (in floats) -- zeroed region first [MAXKEY..DEN]
constexpr size_t OFF_MAXKEY = 0;                       // u32[32] (fallback only)
constexpr size_t OFF_DEN    = 32;                      // f32[32]
constexpr size_t OFF_RW     = 64;                      // f32[32*1024]
constexpr size_t OFF_CW     = OFF_RW + 32 * 1024;      // f32[32*1024]
constexpr size_t OFF_X0N    = OFF_CW + 32 * 1024;      // f32[1024]
constexpr size_t OFF_X1N    = OFF_X0N + 1024;          // f32[1024]
constexpr size_t OFF_AP     = OFF_X1N + 1024;          // f32[32*1024]
constexpr size_t OFF_BP     = OFF_AP + 32 * 1024;      // f32[32*1024]
constexpr size_t OFF_C2     = OFF_BP + 32 * 1024;      // f32[32]
constexpr size_t OFF_RWP    = ((OFF_C2 + 32 + 63) / 64) * 64;  // f32[32][32][1024]
constexpr size_t OFF_DOT    = OFF_RWP;                 // fallback aliases dot here
constexpr size_t OFF_CWP    = OFF_RWP + 32 * 32 * 1024;// f32[32][32][1024]
constexpr size_t OFF_MLOC   = OFF_CWP + 32 * 32 * 1024;// f32[32][32][32]
constexpr size_t WS_NEED_FUSED = OFF_MLOC + 32 * 32 * 32;
constexpr size_t WS_NEED_FALLBACK = OFF_DOT + 1024 * 1024;

__device__ __forceinline__ unsigned fkey(float x) {
  unsigned u = __float_as_uint(x);
  return (u & 0x80000000u) ? ~u : (u | 0x80000000u);
}
__device__ __forceinline__ float funkey(unsigned u) {
  return (u & 0x80000000u) ? __uint_as_float(u & 0x7fffffffu)
                           : __uint_as_float(~u);
}

// ---------------- Ap[b,i], Bp[b,j], c2[b], x0n, x1n ----------------
__global__ __launch_bounds__(256) void k_ab(const float* __restrict__ xt,
                                            const float* __restrict__ tarr,
                                            const float* __restrict__ x0,
                                            const float* __restrict__ x1,
                                            float* __restrict__ ws) {
  __shared__ __align__(16) float xts[ND];
  int b = blockIdx.x >> 2, q = blockIdx.x & 3;
  int tid = threadIdx.x;
  if (tid < ND) xts[tid] = xt[(size_t)b * ND + tid];
  __syncthreads();

  float tb = tarr[b];
  float omt = 1.f - tb;
  float ib2 = 1.f / ((tb + ETA) * (1.f - tb + ETA));

  float xtn = 0.f;
#pragma unroll
  for (int k4 = 0; k4 < ND / 4; k4++) {
    float4 xv = *(const float4*)&xts[k4 * 4];
    xtn += xv.x * xv.x + xv.y * xv.y + xv.z * xv.z + xv.w * xv.w;
  }

  int i = q * 256 + tid;
  float acc0 = 0.f, acc1 = 0.f, n0 = 0.f, n1 = 0.f;
#pragma unroll 8
  for (int k4 = 0; k4 < ND / 4; k4++) {
    float4 xv = *(const float4*)&xts[k4 * 4];
    float4 a = *(const float4*)(x0 + (size_t)i * ND + k4 * 4);
    float4 c = *(const float4*)(x1 + (size_t)i * ND + k4 * 4);
    acc0 += xv.x * a.x + xv.y * a.y + xv.z * a.z + xv.w * a.w;
    acc1 += xv.x * c.x + xv.y * c.y + xv.z * c.z + xv.w * c.w;
    n0 += a.x * a.x + a.y * a.y + a.z * a.z + a.w * a.w;
    n1 += c.x * c.x + c.y * c.y + c.z * c.z + c.w * c.w;
  }
  ws[OFF_AP + (size_t)b * NN + i] =
      fmaf(omt * omt, n0, fmaf(-2.f * omt, acc0, xtn)) * ib2;
  ws[OFF_BP + (size_t)b * NN + i] =
      fmaf(tb * tb, n1, -2.f * tb * acc1) * ib2;
  if (b == 0) {
    ws[OFF_X0N + i] = n0;
    ws[OFF_X1N + i] = n1;
  }
  if (q == 0 && tid == 0) ws[OFF_C2 + b] = 2.f * tb * omt * ib2;
}

// ---------------- kF: fused GEMM + QPR + local max + exp partials ----
__global__ __launch_bounds__(256) void kF(const float* __restrict__ x0,
                                          const float* __restrict__ x1,
                                          const float* __restrict__ sigw,
                                          float* __restrict__ ws) {
  // gemmbuf overlaid: As/Bs during GEMM, rowS/colS during pass B
  __shared__ __align__(16) float gemmbuf[2304];  // 2*32*36 floats
  __shared__ __align__(16) float4 QPRS[32][32];
  __shared__ float ApT[32][33], BpT[32][33];
  __shared__ float x0nS[32], x1nS[32];
  __shared__ unsigned mS[32];

  float (*As)[36] = (float(*)[36])&gemmbuf[0];
  float (*Bs)[36] = (float(*)[36])&gemmbuf[1152];
  float (*rowS)[33] = (float(*)[33])&gemmbuf[0];     // [32][33] = 1056 floats
  float (*colS)[33] = (float(*)[33])&gemmbuf[1056];  // [32][33]

  int tid = threadIdx.x;
  int tx = tid & 15, ty = tid >> 4;
  int jb = blockIdx.x, ib = blockIdx.y;
  int i0 = ib * 32, j0 = jb * 32;

  {
    const float* Ap = ws + OFF_AP;
    const float* Bp = ws + OFF_BP;
#pragma unroll
    for (int rep = 0; rep < 4; rep++) {
      int idx = rep * 256 + tid;
      int bb = idx >> 5, ii = idx & 31;
      ApT[ii][bb] = Ap[(size_t)bb * NN + i0 + ii];
      BpT[ii][bb] = Bp[(size_t)bb * NN + j0 + ii];
    }
    if (tid < 32) {
      x0nS[tid] = ws[OFF_X0N + i0 + tid];
      x1nS[tid] = ws[OFF_X1N + j0 + tid];
      mS[tid] = 0u;
    }
  }

  // GEMM 32x32x128 (2x2 per thread)
  float c00 = 0.f, c01 = 0.f, c10 = 0.f, c11 = 0.f;
  int srow = tid >> 3, sk4 = tid & 7;
  for (int kc = 0; kc < 4; kc++) {
    __syncthreads();
    float4 a = *(const float4*)(x0 + (size_t)(i0 + srow) * ND + kc * 32 + sk4 * 4);
    float4 bb = *(const float4*)(x1 + (size_t)(j0 + srow) * ND + kc * 32 + sk4 * 4);
    As[sk4 * 4 + 0][srow] = a.x;
    As[sk4 * 4 + 1][srow] = a.y;
    As[sk4 * 4 + 2][srow] = a.z;
    As[sk4 * 4 + 3][srow] = a.w;
    Bs[sk4 * 4 + 0][srow] = bb.x;
    Bs[sk4 * 4 + 1][srow] = bb.y;
    Bs[sk4 * 4 + 2][srow] = bb.z;
    Bs[sk4 * 4 + 3][srow] = bb.w;
    __syncthreads();
#pragma unroll
    for (int k = 0; k < 32; k++) {
      float2 av = *(const float2*)&As[k][ty * 2];
      float2 bv = *(const float2*)&Bs[k][tx * 2];
      c00 = fmaf(av.x, bv.x, c00);
      c01 = fmaf(av.x, bv.y, c01);
      c10 = fmaf(av.y, bv.x, c10);
      c11 = fmaf(av.y, bv.y, c11);
    }
  }

  // QPR per point (log2 domain); no dot store needed (fused!)
  float swv = sigw[0];
  float sp = (swv > 20.f) ? swv : log1pf(__expf(swv));
  float dotv[2][2] = {{c00, c01}, {c10, c11}};
#pragma unroll
  for (int r = 0; r < 2; r++) {
#pragma unroll
    for (int c = 0; c < 2; c++) {
      float d01 = x0nS[ty * 2 + r] + x1nS[tx * 2 + c] - 2.f * dotv[r][c];
      float ss = fmaf(sp, sqrtf(fmaxf(d01, 0.f) * (1.f / 128.f)), MIN_SIGMA);
      float Q = -0.72134752044f / (ss * ss);
      float R = -128.f * __log2f(ss);
      QPRS[ty * 2 + r][tx * 2 + c] = make_float4(Q, dotv[r][c] * Q, R, 0.f);
    }
  }
  __syncthreads();  // QPRS ready; all GEMM reads of As/Bs complete

  // pass A: b-lane LOCAL max; also zero colS overlay (As/Bs dead now)
  for (int idx = tid; idx < 1056; idx += 256) ((float*)colS)[idx] = 0.f;
  int b = tid & 31, rep = tid >> 5;
  float c2b = ws[OFF_C2 + b];
  float bpreg[32];
#pragma unroll
  for (int j = 0; j < 32; j++) bpreg[j] = BpT[j][b];
  float m = -3.4e38f;
#pragma unroll
  for (int r = 0; r < 4; r++) {
    int i = rep * 4 + r;
    float ap = ApT[i][b];
#pragma unroll
    for (int j = 0; j < 32; j++) {
      float4 q4 = QPRS[i][j];
      float core = fmaf(ap + bpreg[j], q4.x, fmaf(c2b, q4.y, q4.z));
      m = fmaxf(m, core);
    }
  }
  atomicMax(&mS[b], fkey(m));
  __syncthreads();  // mS final, colS zeroed

  // pass B: exp2 against LOCAL max, accumulate row/col sums
  float m2 = funkey(mS[b]);
  float colreg[32];
#pragma unroll
  for (int j = 0; j < 32; j++) colreg[j] = 0.f;
#pragma unroll
  for (int r = 0; r < 4; r++) {
    int i = rep * 4 + r;
    float ap = ApT[i][b];
    float rs = 0.f;
#pragma unroll
    for (int j = 0; j < 32; j++) {
      float4 q4 = QPRS[i][j];
      float core = fmaf(ap + bpreg[j], q4.x, fmaf(c2b, q4.y, q4.z));
      float w = exp2f(core - m2);
      rs += w;
      colreg[j] += w;
    }
    rowS[i][b] = rs;  // unique owner -> plain store
  }
#pragma unroll
  for (int j = 0; j < 32; j++) atomicAdd(&colS[j][b], colreg[j]);
  __syncthreads();

  // flush partials (unique writer per element -> plain stores)
  float* rwp = ws + OFF_RWP + (size_t)jb * (32 * 1024);  // [jb][b][i]
  float* cwp = ws + OFF_CWP + (size_t)ib * (32 * 1024);  // [ib][b][j]
#pragma unroll
  for (int k = 0; k < 4; k++) {
    int idx = k * 256 + tid;
    int bb = idx >> 5, ii = idx & 31;
    rwp[(size_t)bb * NN + i0 + ii] = rowS[ii][bb];
    cwp[(size_t)bb * NN + j0 + ii] = colS[ii][bb];
  }
  if (tid < 32) ws[OFF_MLOC + ((size_t)ib * 32 + jb) * 32 + tid] = funkey(mS[tid]);
}

// ---------------- kR: rescale-merge partials into rw/cw + den --------
__global__ __launch_bounds__(256) void kR(float* __restrict__ ws) {
  __shared__ float red[256];
  int b = blockIdx.x >> 2, quarter = blockIdx.x & 3;
  int tid = threadIdx.x;

  // global per-b max over 1024 mloc entries (stride 32)
  const float* ml = ws + OFF_MLOC + b;
  float mx = -3.4e38f;
#pragma unroll
  for (int k = 0; k < 4; k++) mx = fmaxf(mx, ml[(size_t)(k * 256 + tid) * 32]);
  red[tid] = mx;
  __syncthreads();
  for (int s = 128; s > 0; s >>= 1) {
    if (tid < s) red[tid] = fmaxf(red[tid], red[tid + s]);
    __syncthreads();
  }
  float mg = red[0];
  __syncthreads();  // allow red reuse below

  int i = quarter * 256 + tid;  // 0..1023 (row index for rw, col index for cw)
  int tb = i >> 5;              // tile index of i
  const float* rwp = ws + OFF_RWP + (size_t)b * NN + i;  // + p*32*1024 over jb
  const float* cwp = ws + OFF_CWP + (size_t)b * NN + i;  // + p*32*1024 over ib
  const float* mlI = ws + OFF_MLOC + (size_t)tb * 1024 + b;  // + p*32   (jb varies)
  const float* mlJ = ws + OFF_MLOC + (size_t)tb * 32 + b;    // + p*1024 (ib varies)
  float s0 = 0.f, s1 = 0.f;
#pragma unroll 8
  for (int p = 0; p < 32; p++) {
    s0 = fmaf(exp2f(mlI[(size_t)p * 32] - mg), rwp[(size_t)p * 32 * 1024], s0);
    s1 = fmaf(exp2f(mlJ[(size_t)p * 1024] - mg), cwp[(size_t)p * 32 * 1024], s1);
  }
  ws[OFF_RW + (size_t)b * NN + i] = s0;
  ws[OFF_CW + (size_t)b * NN + i] = s1;

  // den[b] = sum of all row sums
  red[tid] = s0;
  __syncthreads();
  for (int s = 128; s > 0; s >>= 1) {
    if (tid < s) red[tid] += red[tid + s];
    __syncthreads();
  }
  if (tid == 0) atomicAdd(ws + OFF_DEN + b, red[0]);
}

// ---------------- fallback path (round-3 proven): k1 + k2 atomic -----
__global__ __launch_bounds__(256) void k1(const float* __restrict__ x0,
                                          const float* __restrict__ x1,
                                          const float* __restrict__ sigw,
                                          float* __restrict__ ws) {
  __shared__ __align__(16) float As[32][36];
  __shared__ __align__(16) float Bs[32][36];
  __shared__ __align__(16) float4 QPRS[32][32];
  __shared__ float ApT[32][33], BpT[32][33];
  __shared__ float x0nS[32], x1nS[32];
  __shared__ unsigned mS[32];

  int tid = threadIdx.x;
  int tx = tid & 15, ty = tid >> 4;
  int i0 = blockIdx.y * 32, j0 = blockIdx.x * 32;

  {
    const float* Ap = ws + OFF_AP;
    const float* Bp = ws + OFF_BP;
#pragma unroll
    for (int rep = 0; rep < 4; rep++) {
      int idx = rep * 256 + tid;
      int bb = idx >> 5, ii = idx & 31;
      ApT[ii][bb] = Ap[(size_t)bb * NN + i0 + ii];
      BpT[ii][bb] = Bp[(size_t)bb * NN + j0 + ii];
    }
    if (tid < 32) {
      x0nS[tid] = ws[OFF_X0N + i0 + tid];
      x1nS[tid] = ws[OFF_X1N + j0 + tid];
      mS[tid] = 0u;
    }
  }

  float c00 = 0.f, c01 = 0.f, c10 = 0.f, c11 = 0.f;
  int srow = tid >> 3, sk4 = tid & 7;
  for (int kc = 0; kc < 4; kc++) {
    __syncthreads();
    float4 a = *(const float4*)(x0 + (size_t)(i0 + srow) * ND + kc * 32 + sk4 * 4);
    float4 bb = *(const float4*)(x1 + (size_t)(j0 + srow) * ND + kc * 32 + sk4 * 4);
    As[sk4 * 4 + 0][srow] = a.x;
    As[sk4 * 4 + 1][srow] = a.y;
    As[sk4 * 4 + 2][srow] = a.z;
    As[sk4 * 4 + 3][srow] = a.w;
    Bs[sk4 * 4 + 0][srow] = bb.x;
    Bs[sk4 * 4 + 1][srow] = bb.y;
    Bs[sk4 * 4 + 2][srow] = bb.z;
    Bs[sk4 * 4 + 3][srow] = bb.w;
    __syncthreads();
#pragma unroll
    for (int k = 0; k < 32; k++) {
      float2 av = *(const float2*)&As[k][ty * 2];
      float2 bv = *(const float2*)&Bs[k][tx * 2];
      c00 = fmaf(av.x, bv.x, c00);
      c01 = fmaf(av.x, bv.y, c01);
      c10 = fmaf(av.y, bv.x, c10);
      c11 = fmaf(av.y, bv.y, c11);
    }
  }

  float* dot = ws + OFF_DOT;
  *(float2*)&dot[(size_t)(i0 + ty * 2 + 0) * NN + j0 + tx * 2] = make_float2(c00, c01);
  *(float2*)&dot[(size_t)(i0 + ty * 2 + 1) * NN + j0 + tx * 2] = make_float2(c10, c11);

  float swv = sigw[0];
  float sp = (swv > 20.f) ? swv : log1pf(__expf(swv));
  float dotv[2][2] = {{c00, c01}, {c10, c11}};
#pragma unroll
  for (int r = 0; r < 2; r++) {
#pragma unroll
    for (int c = 0; c < 2; c++) {
      float d01 = x0nS[ty * 2 + r] + x1nS[tx * 2 + c] - 2.f * dotv[r][c];
      float ss = fmaf(sp, sqrtf(fmaxf(d01, 0.f) * (1.f / 128.f)), MIN_SIGMA);
      float Q = -0.72134752044f / (ss * ss);
      float R = -128.f * __log2f(ss);
      QPRS[ty * 2 + r][tx * 2 + c] = make_float4(Q, dotv[r][c] * Q, R, 0.f);
    }
  }
  __syncthreads();

  int b = tid & 31, rep = tid >> 5;
  float c2b = ws[OFF_C2 + b];
  float bpreg[32];
#pragma unroll
  for (int j = 0; j < 32; j++) bpreg[j] = BpT[j][b];
  float m = -3.4e38f;
#pragma unroll
  for (int r = 0; r < 4; r++) {
    int i = rep * 4 + r;
    float ap = ApT[i][b];
#pragma unroll
    for (int j = 0; j < 32; j++) {
      float4 q4 = QPRS[i][j];
      float core = fmaf(ap + bpreg[j], q4.x, fmaf(c2b, q4.y, q4.z));
      m = fmaxf(m, core);
    }
  }
  atomicMax(&mS[b], fkey(m));
  __syncthreads();
  if (tid < 32) atomicMax((unsigned*)ws + OFF_MAXKEY + tid, mS[tid]);
}

__global__ __launch_bounds__(256) void k2(const float* __restrict__ sigw,
                                          float* __restrict__ ws) {
  __shared__ __align__(16) float4 QPRS[32][32];
  __shared__ float ApT[32][33], BpT[32][33];
  __shared__ float colS[32][33], rowS[32][33];
  __shared__ float x0nS[32], x1nS[32];
  __shared__ float denS[32];

  int tid = threadIdx.x;
  int tx = tid & 15, ty = tid >> 4;
  int i0 = blockIdx.y * 32, j0 = blockIdx.x * 32;

  {
    const float* Ap = ws + OFF_AP;
    const float* Bp = ws + OFF_BP;
#pragma unroll
    for (int rep = 0; rep < 4; rep++) {
      int idx = rep * 256 + tid;
      int bb = idx >> 5, ii = idx & 31;
      ApT[ii][bb] = Ap[(size_t)bb * NN + i0 + ii];
      BpT[ii][bb] = Bp[(size_t)bb * NN + j0 + ii];
      colS[ii][bb] = 0.f;
    }
    if (tid < 32) {
      x0nS[tid] = ws[OFF_X0N + i0 + tid];
      x1nS[tid] = ws[OFF_X1N + j0 + tid];
      denS[tid] = 0.f;
    }
  }

  const float* dot = ws + OFF_DOT;
  float2 dv0 = *(const float2*)&dot[(size_t)(i0 + ty * 2 + 0) * NN + j0 + tx * 2];
  float2 dv1 = *(const float2*)&dot[(size_t)(i0 + ty * 2 + 1) * NN + j0 + tx * 2];
  float dotv[2][2] = {{dv0.x, dv0.y}, {dv1.x, dv1.y}};
  float swv = sigw[0];
  float sp = (swv > 20.f) ? swv : log1pf(__expf(swv));

  __syncthreads();

#pragma unroll
  for (int r = 0; r < 2; r++) {
#pragma unroll
    for (int c = 0; c < 2; c++) {
      float d01 = x0nS[ty * 2 + r] + x1nS[tx * 2 + c] - 2.f * dotv[r][c];
      float ss = fmaf(sp, sqrtf(fmaxf(d01, 0.f) * (1.f / 128.f)), MIN_SIGMA);
      float Q = -0.72134752044f / (ss * ss);
      float R = -128.f * __log2f(ss);
      QPRS[ty * 2 + r][tx * 2 + c] = make_float4(Q, dotv[r][c] * Q, R, 0.f);
    }
  }
  __syncthreads();

  int b = tid & 31, rep = tid >> 5;
  float c2b = ws[OFF_C2 + b];
  float m2 = funkey(((const unsigned*)ws)[OFF_MAXKEY + b]);
  float bpreg[32];
#pragma unroll
  for (int j = 0; j < 32; j++) bpreg[j] = BpT[j][b];
  float colreg[32];
#pragma unroll
  for (int j = 0; j < 32; j++) colreg[j] = 0.f;
  float dreg = 0.f;
#pragma unroll
  for (int r = 0; r < 4; r++) {
    int i = rep * 4 + r;
    float ap = ApT[i][b];
    float rs = 0.f;
#pragma unroll
    for (int j = 0; j < 32; j++) {
      float4 q4 = QPRS[i][j];
      float core = fmaf(ap + bpreg[j], q4.x, fmaf(c2b, q4.y, q4.z));
      float w = exp2f(core - m2);
      rs += w;
      colreg[j] += w;
    }
    rowS[i][b] = rs;
    dreg += rs;
  }
#pragma unroll
  for (int j = 0; j < 32; j++) atomicAdd(&colS[j][b], colreg[j]);
  atomicAdd(&denS[b], dreg);
  __syncthreads();

  float* rw = ws + OFF_RW;
  float* cw = ws + OFF_CW;
#pragma unroll
  for (int k = 0; k < 4; k++) {
    int idx = k * 256 + tid;
    int bb = idx >> 5, ii = idx & 31;
    atomicAdd(&rw[(size_t)bb * NN + i0 + ii], rowS[ii][bb]);
    atomicAdd(&cw[(size_t)bb * NN + j0 + ii], colS[ii][bb]);
  }
  if (tid < 32) atomicAdd(ws + OFF_DEN + tid, denS[tid]);
}

// ---------------- k3: weighted combine + output ----------------
__global__ __launch_bounds__(256) void k3(const float* __restrict__ xt,
                                          const float* __restrict__ tarr,
                                          const float* __restrict__ x0,
                                          const float* __restrict__ x1,
                                          const float* __restrict__ ws,
                                          float* __restrict__ out) {
  int b = blockIdx.x >> 2, dq = blockIdx.x & 3;
  int tid = threadIdx.x;
  int d = dq * 32 + (tid & 31);
  int h = tid >> 5;  // 0..7, each handles 128 rows
  const float* rw = ws + OFF_RW + (size_t)b * NN;
  const float* cw = ws + OFF_CW + (size_t)b * NN;
  float a0 = 0.f, a1 = 0.f;
  int ibeg = h * 128;
#pragma unroll 4
  for (int k = 0; k < 128; k++) {
    int i = ibeg + k;
    a0 = fmaf(rw[i], x0[(size_t)i * ND + d], a0);
    a1 = fmaf(cw[i], x1[(size_t)i * ND + d], a1);
  }
  __shared__ float s0[8][32], s1[8][32];
  s0[h][tid & 31] = a0;
  s1[h][tid & 31] = a1;
  __syncthreads();
  if (tid < 32) {
    float A0 = 0.f, A1 = 0.f;
#pragma unroll
    for (int hh = 0; hh < 8; hh++) {
      A0 += s0[hh][tid];
      A1 += s1[hh][tid];
    }
    float tb = tarr[b];
    float den = ws[OFF_DEN + b];
    float ct = (1.f - 2.f * tb) / (2.f * (tb + ETA) * (1.f - tb + ETA));
    float av = -1.f - ct * (1.f - tb);
    float bv = 1.f - ct * tb;
    float den_c = fmaxf(den, 1e-12f);
    out[(size_t)b * ND + d] =
        (ct * xt[(size_t)b * ND + d] * den + av * A0 + bv * A1) / den_c;
  }
}

extern "C" void kernel_launch(void* const* d_in, const int* in_sizes, int n_in,
                              void* d_out, int out_size, void* d_ws, size_t ws_size,
                              hipStream_t stream) {
  const float* xt = (const float*)d_in[0];
  const float* t = (const float*)d_in[1];
  const float* x0 = (const float*)d_in[2];
  const float* x1 = (const float*)d_in[3];
  const float* sw = (const float*)d_in[4];
  float* out = (float*)d_out;
  float* ws = (float*)d_ws;

  bool fused = ws_size >= WS_NEED_FUSED * sizeof(float);

  if (fused) {
    hipMemsetAsync(ws, 0, 64 * sizeof(float), stream);  // maxkey+den
    k_ab<<<128, 256, 0, stream>>>(xt, t, x0, x1, ws);
    kF<<<dim3(32, 32), 256, 0, stream>>>(x0, x1, sw, ws);
    kR<<<128, 256, 0, stream>>>(ws);
  } else {
    hipMemsetAsync(ws, 0, OFF_X0N * sizeof(float), stream);
    k_ab<<<128, 256, 0, stream>>>(xt, t, x0, x1, ws);
    k1<<<dim3(32, 32), 256, 0, stream>>>(x0, x1, sw, ws);
    k2<<<dim3(32, 32), 256, 0, stream>>>(sw, ws);
  }
  k3<<<128, 256, 0, stream>>>(xt, t, x0, x1, ws, out);
}

// Round 9
// 161.787 us; speedup vs baseline: 1.0877x; 1.0157x over previous
//
#include <hip/hip_runtime.h>
#include <math.h>

#define ETA 1e-5f
#define MIN_SIGMA 1e-6f

constexpr int NN = 1024;  // N0 == N1
constexpr int ND = 128;   // D

// ws layout (in floats) -- zeroed region first [MAXKEY..DEN]
constexpr size_t OFF_MAXKEY = 0;                       // u32[32] (fallback only)
constexpr size_t OFF_DEN    = 32;                      // f32[32]
constexpr size_t OFF_RW     = 64;                      // f32[32*1024]
constexpr size_t OFF_CW     = OFF_RW + 32 * 1024;      // f32[32*1024]
constexpr size_t OFF_X0N    = OFF_CW + 32 * 1024;      // f32[1024]
constexpr size_t OFF_X1N    = OFF_X0N + 1024;          // f32[1024]
constexpr size_t OFF_AP     = OFF_X1N + 1024;          // f32[32*1024]
constexpr size_t OFF_BP     = OFF_AP + 32 * 1024;      // f32[32*1024]
constexpr size_t OFF_C2     = OFF_BP + 32 * 1024;      // f32[32]
constexpr size_t OFF_RWP    = ((OFF_C2 + 32 + 63) / 64) * 64;  // f32[32][32][1024]
constexpr size_t OFF_DOT    = OFF_RWP;                 // fallback aliases dot here
constexpr size_t OFF_CWP    = OFF_RWP + 32 * 32 * 1024;// f32[32][32][1024]
constexpr size_t OFF_MLOC   = OFF_CWP + 32 * 32 * 1024;// f32[32][32][32]
constexpr size_t WS_NEED_FUSED = OFF_MLOC + 32 * 32 * 32;
constexpr size_t WS_NEED_FALLBACK = OFF_DOT + 1024 * 1024;

__device__ __forceinline__ unsigned fkey(float x) {
  unsigned u = __float_as_uint(x);
  return (u & 0x80000000u) ? ~u : (u | 0x80000000u);
}
__device__ __forceinline__ float funkey(unsigned u) {
  return (u & 0x80000000u) ? __uint_as_float(u & 0x7fffffffu)
                           : __uint_as_float(~u);
}

// ---------------- Ap[b,i], Bp[b,j], c2[b], x0n, x1n ----------------
__global__ __launch_bounds__(256) void k_ab(const float* __restrict__ xt,
                                            const float* __restrict__ tarr,
                                            const float* __restrict__ x0,
                                            const float* __restrict__ x1,
                                            float* __restrict__ ws) {
  __shared__ __align__(16) float xts[ND];
  int b = blockIdx.x >> 2, q = blockIdx.x & 3;
  int tid = threadIdx.x;
  if (tid < ND) xts[tid] = xt[(size_t)b * ND + tid];
  __syncthreads();

  float tb = tarr[b];
  float omt = 1.f - tb;
  float ib2 = 1.f / ((tb + ETA) * (1.f - tb + ETA));

  float xtn = 0.f;
#pragma unroll
  for (int k4 = 0; k4 < ND / 4; k4++) {
    float4 xv = *(const float4*)&xts[k4 * 4];
    xtn += xv.x * xv.x + xv.y * xv.y + xv.z * xv.z + xv.w * xv.w;
  }

  int i = q * 256 + tid;
  float acc0 = 0.f, acc1 = 0.f, n0 = 0.f, n1 = 0.f;
#pragma unroll 8
  for (int k4 = 0; k4 < ND / 4; k4++) {
    float4 xv = *(const float4*)&xts[k4 * 4];
    float4 a = *(const float4*)(x0 + (size_t)i * ND + k4 * 4);
    float4 c = *(const float4*)(x1 + (size_t)i * ND + k4 * 4);
    acc0 += xv.x * a.x + xv.y * a.y + xv.z * a.z + xv.w * a.w;
    acc1 += xv.x * c.x + xv.y * c.y + xv.z * c.z + xv.w * c.w;
    n0 += a.x * a.x + a.y * a.y + a.z * a.z + a.w * a.w;
    n1 += c.x * c.x + c.y * c.y + c.z * c.z + c.w * c.w;
  }
  ws[OFF_AP + (size_t)b * NN + i] =
      fmaf(omt * omt, n0, fmaf(-2.f * omt, acc0, xtn)) * ib2;
  ws[OFF_BP + (size_t)b * NN + i] =
      fmaf(tb * tb, n1, -2.f * tb * acc1) * ib2;
  if (b == 0) {
    ws[OFF_X0N + i] = n0;
    ws[OFF_X1N + i] = n1;
  }
  if (q == 0 && tid == 0) ws[OFF_C2 + b] = 2.f * tb * omt * ib2;
}

// ---------------- kF: fused GEMM + QPR + local max + exp partials ----
// Pass A/B thread layout: (b = tid&31, jg = tid>>5) -> thread owns batch b
// and 4 columns j = jg*4..jg*4+3, loops all 32 rows. Only 4-element register
// arrays -> no spill (round-7 kF kept 64+ floats live at VGPR_Count=52).
__global__ __launch_bounds__(256) void kF(const float* __restrict__ x0,
                                          const float* __restrict__ x1,
                                          const float* __restrict__ sigw,
                                          float* __restrict__ ws) {
  // gemmbuf overlaid: As/Bs during GEMM, rowP/colS during pass B
  __shared__ __align__(16) float gemmbuf[2304];  // 2*32*36 floats
  __shared__ __align__(16) float4 QPRS[32][32];
  __shared__ float ApT[32][33], BpT[32][33];
  __shared__ float x0nS[32], x1nS[32];
  __shared__ unsigned mS[32];

  float (*As)[36] = (float(*)[36])&gemmbuf[0];
  float (*Bs)[36] = (float(*)[36])&gemmbuf[1152];
  float (*rowP)[33] = (float(*)[33])&gemmbuf[0];     // [32][33] = 1056 floats
  float (*colS)[33] = (float(*)[33])&gemmbuf[1056];  // [32][33]

  int tid = threadIdx.x;
  int tx = tid & 15, ty = tid >> 4;
  int jb = blockIdx.x, ib = blockIdx.y;
  int i0 = ib * 32, j0 = jb * 32;

  {
    const float* Ap = ws + OFF_AP;
    const float* Bp = ws + OFF_BP;
#pragma unroll
    for (int rep = 0; rep < 4; rep++) {
      int idx = rep * 256 + tid;
      int bb = idx >> 5, ii = idx & 31;
      ApT[ii][bb] = Ap[(size_t)bb * NN + i0 + ii];
      BpT[ii][bb] = Bp[(size_t)bb * NN + j0 + ii];
    }
    if (tid < 32) {
      x0nS[tid] = ws[OFF_X0N + i0 + tid];
      x1nS[tid] = ws[OFF_X1N + j0 + tid];
      mS[tid] = 0u;
    }
  }

  // GEMM 32x32x128 (2x2 per thread)
  float c00 = 0.f, c01 = 0.f, c10 = 0.f, c11 = 0.f;
  int srow = tid >> 3, sk4 = tid & 7;
  for (int kc = 0; kc < 4; kc++) {
    __syncthreads();
    float4 a = *(const float4*)(x0 + (size_t)(i0 + srow) * ND + kc * 32 + sk4 * 4);
    float4 bb = *(const float4*)(x1 + (size_t)(j0 + srow) * ND + kc * 32 + sk4 * 4);
    As[sk4 * 4 + 0][srow] = a.x;
    As[sk4 * 4 + 1][srow] = a.y;
    As[sk4 * 4 + 2][srow] = a.z;
    As[sk4 * 4 + 3][srow] = a.w;
    Bs[sk4 * 4 + 0][srow] = bb.x;
    Bs[sk4 * 4 + 1][srow] = bb.y;
    Bs[sk4 * 4 + 2][srow] = bb.z;
    Bs[sk4 * 4 + 3][srow] = bb.w;
    __syncthreads();
#pragma unroll
    for (int k = 0; k < 32; k++) {
      float2 av = *(const float2*)&As[k][ty * 2];
      float2 bv = *(const float2*)&Bs[k][tx * 2];
      c00 = fmaf(av.x, bv.x, c00);
      c01 = fmaf(av.x, bv.y, c01);
      c10 = fmaf(av.y, bv.x, c10);
      c11 = fmaf(av.y, bv.y, c11);
    }
  }

  // QPR per point (log2 domain); no dot store needed (fused)
  float swv = sigw[0];
  float sp = (swv > 20.f) ? swv : log1pf(__expf(swv));
  float dotv[2][2] = {{c00, c01}, {c10, c11}};
#pragma unroll
  for (int r = 0; r < 2; r++) {
#pragma unroll
    for (int c = 0; c < 2; c++) {
      float d01 = x0nS[ty * 2 + r] + x1nS[tx * 2 + c] - 2.f * dotv[r][c];
      float ss = fmaf(sp, sqrtf(fmaxf(d01, 0.f) * (1.f / 128.f)), MIN_SIGMA);
      float Q = -0.72134752044f / (ss * ss);
      float R = -128.f * __log2f(ss);
      QPRS[ty * 2 + r][tx * 2 + c] = make_float4(Q, dotv[r][c] * Q, R, 0.f);
    }
  }
  __syncthreads();  // QPRS ready; all GEMM reads of As/Bs complete

  // pass A: (b,jg) local max over 32 rows x 4 cols; zero rowP overlay
  for (int idx = tid; idx < 1056; idx += 256) ((float*)rowP)[idx] = 0.f;
  int b = tid & 31, jg = tid >> 5;
  float c2b = ws[OFF_C2 + b];
  float bp4[4];
#pragma unroll
  for (int jj = 0; jj < 4; jj++) bp4[jj] = BpT[jg * 4 + jj][b];
  float m = -3.4e38f;
#pragma unroll
  for (int i = 0; i < 32; i++) {
    float ap = ApT[i][b];
#pragma unroll
    for (int jj = 0; jj < 4; jj++) {
      float4 q4 = QPRS[i][jg * 4 + jj];
      float core = fmaf(ap + bp4[jj], q4.x, fmaf(c2b, q4.y, q4.z));
      m = fmaxf(m, core);
    }
  }
  atomicMax(&mS[b], fkey(m));
  __syncthreads();  // mS final, rowP zeroed

  // pass B: exp2 against LOCAL max; col sums private (unique writer),
  // row sums via LDS atomicAdd (8 threads per (i,b))
  float m2 = funkey(mS[b]);
  float col4[4] = {0.f, 0.f, 0.f, 0.f};
#pragma unroll
  for (int i = 0; i < 32; i++) {
    float ap = ApT[i][b];
    float rs = 0.f;
#pragma unroll
    for (int jj = 0; jj < 4; jj++) {
      float4 q4 = QPRS[i][jg * 4 + jj];
      float core = fmaf(ap + bp4[jj], q4.x, fmaf(c2b, q4.y, q4.z));
      float w = exp2f(core - m2);
      rs += w;
      col4[jj] += w;
    }
    atomicAdd(&rowP[i][b], rs);
  }
#pragma unroll
  for (int jj = 0; jj < 4; jj++) colS[jg * 4 + jj][b] = col4[jj];  // unique owner
  __syncthreads();

  // flush partials (unique writer per element -> plain stores)
  float* rwp = ws + OFF_RWP + (size_t)jb * (32 * 1024);  // [jb][b][i]
  float* cwp = ws + OFF_CWP + (size_t)ib * (32 * 1024);  // [ib][b][j]
#pragma unroll
  for (int k = 0; k < 4; k++) {
    int idx = k * 256 + tid;
    int bb = idx >> 5, ii = idx & 31;
    rwp[(size_t)bb * NN + i0 + ii] = rowP[ii][bb];
    cwp[(size_t)bb * NN + j0 + ii] = colS[ii][bb];
  }
  if (tid < 32) ws[OFF_MLOC + ((size_t)ib * 32 + jb) * 32 + tid] = funkey(mS[tid]);
}

// ---------------- kR: rescale-merge partials into rw/cw + den --------
__global__ __launch_bounds__(256) void kR(float* __restrict__ ws) {
  __shared__ float red[256];
  int b = blockIdx.x >> 2, quarter = blockIdx.x & 3;
  int tid = threadIdx.x;

  // global per-b max over 1024 mloc entries (stride 32)
  const float* ml = ws + OFF_MLOC + b;
  float mx = -3.4e38f;
#pragma unroll
  for (int k = 0; k < 4; k++) mx = fmaxf(mx, ml[(size_t)(k * 256 + tid) * 32]);
  red[tid] = mx;
  __syncthreads();
  for (int s = 128; s > 0; s >>= 1) {
    if (tid < s) red[tid] = fmaxf(red[tid], red[tid + s]);
    __syncthreads();
  }
  float mg = red[0];
  __syncthreads();  // allow red reuse below

  int i = quarter * 256 + tid;  // 0..1023 (row index for rw, col index for cw)
  int tb = i >> 5;              // tile index of i
  const float* rwp = ws + OFF_RWP + (size_t)b * NN + i;  // + p*32*1024 over jb
  const float* cwp = ws + OFF_CWP + (size_t)b * NN + i;  // + p*32*1024 over ib
  const float* mlI = ws + OFF_MLOC + (size_t)tb * 1024 + b;  // + p*32   (jb varies)
  const float* mlJ = ws + OFF_MLOC + (size_t)tb * 32 + b;    // + p*1024 (ib varies)
  float s0 = 0.f, s1 = 0.f;
#pragma unroll 8
  for (int p = 0; p < 32; p++) {
    s0 = fmaf(exp2f(mlI[(size_t)p * 32] - mg), rwp[(size_t)p * 32 * 1024], s0);
    s1 = fmaf(exp2f(mlJ[(size_t)p * 1024] - mg), cwp[(size_t)p * 32 * 1024], s1);
  }
  ws[OFF_RW + (size_t)b * NN + i] = s0;
  ws[OFF_CW + (size_t)b * NN + i] = s1;

  // den[b] = sum of all row sums
  red[tid] = s0;
  __syncthreads();
  for (int s = 128; s > 0; s >>= 1) {
    if (tid < s) red[tid] += red[tid + s];
    __syncthreads();
  }
  if (tid == 0) atomicAdd(ws + OFF_DEN + b, red[0]);
}

// ---------------- fallback path (round-3 proven): k1 + k2 atomic -----
__global__ __launch_bounds__(256) void k1(const float* __restrict__ x0,
                                          const float* __restrict__ x1,
                                          const float* __restrict__ sigw,
                                          float* __restrict__ ws) {
  __shared__ __align__(16) float As[32][36];
  __shared__ __align__(16) float Bs[32][36];
  __shared__ __align__(16) float4 QPRS[32][32];
  __shared__ float ApT[32][33], BpT[32][33];
  __shared__ float x0nS[32], x1nS[32];
  __shared__ unsigned mS[32];

  int tid = threadIdx.x;
  int tx = tid & 15, ty = tid >> 4;
  int i0 = blockIdx.y * 32, j0 = blockIdx.x * 32;

  {
    const float* Ap = ws + OFF_AP;
    const float* Bp = ws + OFF_BP;
#pragma unroll
    for (int rep = 0; rep < 4; rep++) {
      int idx = rep * 256 + tid;
      int bb = idx >> 5, ii = idx & 31;
      ApT[ii][bb] = Ap[(size_t)bb * NN + i0 + ii];
      BpT[ii][bb] = Bp[(size_t)bb * NN + j0 + ii];
    }
    if (tid < 32) {
      x0nS[tid] = ws[OFF_X0N + i0 + tid];
      x1nS[tid] = ws[OFF_X1N + j0 + tid];
      mS[tid] = 0u;
    }
  }

  float c00 = 0.f, c01 = 0.f, c10 = 0.f, c11 = 0.f;
  int srow = tid >> 3, sk4 = tid & 7;
  for (int kc = 0; kc < 4; kc++) {
    __syncthreads();
    float4 a = *(const float4*)(x0 + (size_t)(i0 + srow) * ND + kc * 32 + sk4 * 4);
    float4 bb = *(const float4*)(x1 + (size_t)(j0 + srow) * ND + kc * 32 + sk4 * 4);
    As[sk4 * 4 + 0][srow] = a.x;
    As[sk4 * 4 + 1][srow] = a.y;
    As[sk4 * 4 + 2][srow] = a.z;
    As[sk4 * 4 + 3][srow] = a.w;
    Bs[sk4 * 4 + 0][srow] = bb.x;
    Bs[sk4 * 4 + 1][srow] = bb.y;
    Bs[sk4 * 4 + 2][srow] = bb.z;
    Bs[sk4 * 4 + 3][srow] = bb.w;
    __syncthreads();
#pragma unroll
    for (int k = 0; k < 32; k++) {
      float2 av = *(const float2*)&As[k][ty * 2];
      float2 bv = *(const float2*)&Bs[k][tx * 2];
      c00 = fmaf(av.x, bv.x, c00);
      c01 = fmaf(av.x, bv.y, c01);
      c10 = fmaf(av.y, bv.x, c10);
      c11 = fmaf(av.y, bv.y, c11);
    }
  }

  float* dot = ws + OFF_DOT;
  *(float2*)&dot[(size_t)(i0 + ty * 2 + 0) * NN + j0 + tx * 2] = make_float2(c00, c01);
  *(float2*)&dot[(size_t)(i0 + ty * 2 + 1) * NN + j0 + tx * 2] = make_float2(c10, c11);

  float swv = sigw[0];
  float sp = (swv > 20.f) ? swv : log1pf(__expf(swv));
  float dotv[2][2] = {{c00, c01}, {c10, c11}};
#pragma unroll
  for (int r = 0; r < 2; r++) {
#pragma unroll
    for (int c = 0; c < 2; c++) {
      float d01 = x0nS[ty * 2 + r] + x1nS[tx * 2 + c] - 2.f * dotv[r][c];
      float ss = fmaf(sp, sqrtf(fmaxf(d01, 0.f) * (1.f / 128.f)), MIN_SIGMA);
      float Q = -0.72134752044f / (ss * ss);
      float R = -128.f * __log2f(ss);
      QPRS[ty * 2 + r][tx * 2 + c] = make_float4(Q, dotv[r][c] * Q, R, 0.f);
    }
  }
  __syncthreads();

  int b = tid & 31, rep = tid >> 5;
  float c2b = ws[OFF_C2 + b];
  float bpreg[32];
#pragma unroll
  for (int j = 0; j < 32; j++) bpreg[j] = BpT[j][b];
  float m = -3.4e38f;
#pragma unroll
  for (int r = 0; r < 4; r++) {
    int i = rep * 4 + r;
    float ap = ApT[i][b];
#pragma unroll
    for (int j = 0; j < 32; j++) {
      float4 q4 = QPRS[i][j];
      float core = fmaf(ap + bpreg[j], q4.x, fmaf(c2b, q4.y, q4.z));
      m = fmaxf(m, core);
    }
  }
  atomicMax(&mS[b], fkey(m));
  __syncthreads();
  if (tid < 32) atomicMax((unsigned*)ws + OFF_MAXKEY + tid, mS[tid]);
}

__global__ __launch_bounds__(256) void k2(const float* __restrict__ sigw,
                                          float* __restrict__ ws) {
  __shared__ __align__(16) float4 QPRS[32][32];
  __shared__ float ApT[32][33], BpT[32][33];
  __shared__ float colS[32][33], rowS[32][33];
  __shared__ float x0nS[32], x1nS[32];
  __shared__ float denS[32];

  int tid = threadIdx.x;
  int tx = tid & 15, ty = tid >> 4;
  int i0 = blockIdx.y * 32, j0 = blockIdx.x * 32;

  {
    const float* Ap = ws + OFF_AP;
    const float* Bp = ws + OFF_BP;
#pragma unroll
    for (int rep = 0; rep < 4; rep++) {
      int idx = rep * 256 + tid;
      int bb = idx >> 5, ii = idx & 31;
      ApT[ii][bb] = Ap[(size_t)bb * NN + i0 + ii];
      BpT[ii][bb] = Bp[(size_t)bb * NN + j0 + ii];
      colS[ii][bb] = 0.f;
    }
    if (tid < 32) {
      x0nS[tid] = ws[OFF_X0N + i0 + tid];
      x1nS[tid] = ws[OFF_X1N + j0 + tid];
      denS[tid] = 0.f;
    }
  }

  const float* dot = ws + OFF_DOT;
  float2 dv0 = *(const float2*)&dot[(size_t)(i0 + ty * 2 + 0) * NN + j0 + tx * 2];
  float2 dv1 = *(const float2*)&dot[(size_t)(i0 + ty * 2 + 1) * NN + j0 + tx * 2];
  float dotv[2][2] = {{dv0.x, dv0.y}, {dv1.x, dv1.y}};
  float swv = sigw[0];
  float sp = (swv > 20.f) ? swv : log1pf(__expf(swv));

  __syncthreads();

#pragma unroll
  for (int r = 0; r < 2; r++) {
#pragma unroll
    for (int c = 0; c < 2; c++) {
      float d01 = x0nS[ty * 2 + r] + x1nS[tx * 2 + c] - 2.f * dotv[r][c];
      float ss = fmaf(sp, sqrtf(fmaxf(d01, 0.f) * (1.f / 128.f)), MIN_SIGMA);
      float Q = -0.72134752044f / (ss * ss);
      float R = -128.f * __log2f(ss);
      QPRS[ty * 2 + r][tx * 2 + c] = make_float4(Q, dotv[r][c] * Q, R, 0.f);
    }
  }
  __syncthreads();

  int b = tid & 31, rep = tid >> 5;
  float c2b = ws[OFF_C2 + b];
  float m2 = funkey(((const unsigned*)ws)[OFF_MAXKEY + b]);
  float bpreg[32];
#pragma unroll
  for (int j = 0; j < 32; j++) bpreg[j] = BpT[j][b];
  float colreg[32];
#pragma unroll
  for (int j = 0; j < 32; j++) colreg[j] = 0.f;
  float dreg = 0.f;
#pragma unroll
  for (int r = 0; r < 4; r++) {
    int i = rep * 4 + r;
    float ap = ApT[i][b];
    float rs = 0.f;
#pragma unroll
    for (int j = 0; j < 32; j++) {
      float4 q4 = QPRS[i][j];
      float core = fmaf(ap + bpreg[j], q4.x, fmaf(c2b, q4.y, q4.z));
      float w = exp2f(core - m2);
      rs += w;
      colreg[j] += w;
    }
    rowS[i][b] = rs;
    dreg += rs;
  }
#pragma unroll
  for (int j = 0; j < 32; j++) atomicAdd(&colS[j][b], colreg[j]);
  atomicAdd(&denS[b], dreg);
  __syncthreads();

  float* rw = ws + OFF_RW;
  float* cw = ws + OFF_CW;
#pragma unroll
  for (int k = 0; k < 4; k++) {
    int idx = k * 256 + tid;
    int bb = idx >> 5, ii = idx & 31;
    atomicAdd(&rw[(size_t)bb * NN + i0 + ii], rowS[ii][bb]);
    atomicAdd(&cw[(size_t)bb * NN + j0 + ii], colS[ii][bb]);
  }
  if (tid < 32) atomicAdd(ws + OFF_DEN + tid, denS[tid]);
}

// ---------------- k3: weighted combine + output ----------------
__global__ __launch_bounds__(256) void k3(const float* __restrict__ xt,
                                          const float* __restrict__ tarr,
                                          const float* __restrict__ x0,
                                          const float* __restrict__ x1,
                                          const float* __restrict__ ws,
                                          float* __restrict__ out) {
  int b = blockIdx.x >> 2, dq = blockIdx.x & 3;
  int tid = threadIdx.x;
  int d = dq * 32 + (tid & 31);
  int h = tid >> 5;  // 0..7, each handles 128 rows
  const float* rw = ws + OFF_RW + (size_t)b * NN;
  const float* cw = ws + OFF_CW + (size_t)b * NN;
  float a0 = 0.f, a1 = 0.f;
  int ibeg = h * 128;
#pragma unroll 4
  for (int k = 0; k < 128; k++) {
    int i = ibeg + k;
    a0 = fmaf(rw[i], x0[(size_t)i * ND + d], a0);
    a1 = fmaf(cw[i], x1[(size_t)i * ND + d], a1);
  }
  __shared__ float s0[8][32], s1[8][32];
  s0[h][tid & 31] = a0;
  s1[h][tid & 31] = a1;
  __syncthreads();
  if (tid < 32) {
    float A0 = 0.f, A1 = 0.f;
#pragma unroll
    for (int hh = 0; hh < 8; hh++) {
      A0 += s0[hh][tid];
      A1 += s1[hh][tid];
    }
    float tb = tarr[b];
    float den = ws[OFF_DEN + b];
    float ct = (1.f - 2.f * tb) / (2.f * (tb + ETA) * (1.f - tb + ETA));
    float av = -1.f - ct * (1.f - tb);
    float bv = 1.f - ct * tb;
    float den_c = fmaxf(den, 1e-12f);
    out[(size_t)b * ND + d] =
        (ct * xt[(size_t)b * ND + d] * den + av * A0 + bv * A1) / den_c;
  }
}

extern "C" void kernel_launch(void* const* d_in, const int* in_sizes, int n_in,
                              void* d_out, int out_size, void* d_ws, size_t ws_size,
                              hipStream_t stream) {
  const float* xt = (const float*)d_in[0];
  const float* t = (const float*)d_in[1];
  const float* x0 = (const float*)d_in[2];
  const float* x1 = (const float*)d_in[3];
  const float* sw = (const float*)d_in[4];
  float* out = (float*)d_out;
  float* ws = (float*)d_ws;

  bool fused = ws_size >= WS_NEED_FUSED * sizeof(float);

  if (fused) {
    hipMemsetAsync(ws, 0, 64 * sizeof(float), stream);  // maxkey+den
    k_ab<<<128, 256, 0, stream>>>(xt, t, x0, x1, ws);
    kF<<<dim3(32, 32), 256, 0, stream>>>(x0, x1, sw, ws);
    kR<<<128, 256, 0, stream>>>(ws);
  } else {
    hipMemsetAsync(ws, 0, OFF_X0N * sizeof(float), stream);
    k_ab<<<128, 256, 0, stream>>>(xt, t, x0, x1, ws);
    k1<<<dim3(32, 32), 256, 0, stream>>>(x0, x1, sw, ws);
    k2<<<dim3(32, 32), 256, 0, stream>>>(sw, ws);
  }
  k3<<<32 * 4, 256, 0, stream>>>(xt, t, x0, x1, ws, out);
}